// Round 10
// baseline (88.740 us; speedup 1.0000x reference)
//
#include <hip/hip_runtime.h>
#include <type_traits>
#include <utility>

#define CDIM   45
#define LMAXX  8
#define WAVES_PB 4
#define VOXPB  64
#define VDIM   64
#define NSPLIT 2                        // vector-split across blocks
#define VPT    (VDIM / NSPLIT / WAVES_PB)   // 8 vectors per wave
#define TILEF  (VOXPB * CDIM)           // 2880 floats per tile

// ---------------- compile-time SH constant tables ----------------
// Normalization CP[m][l] folded INTO the Q-recurrence (p_l = Q_l * CP[m][l]);
// wmod folded into the A/B recurrence seed.
constexpr double PI_D = 3.14159265358979323846;

constexpr double dfactd(int n){ double o=1.0; for(int k=n;k>1;k-=2) o*=k; return o; }
constexpr double factd (int n){ double o=1.0; for(int k=2;k<=n;++k) o*=k; return o; }
constexpr double csqrtd(double x){
  if(x<=0.0) return 0.0;
  double g = x>1.0 ? x : 1.0;
  for(int i=0;i<200;++i) g = 0.5*(g + x/g);
  return g;
}

constexpr double CPf(int m, int l){
  double K = csqrtd((2.0*l+1.0)/(4.0*PI_D)*factd(l-m)/factd(l+m));
  if (m==0) return K;
  return ((m&1)?-1.0:1.0)*csqrtd(2.0)*K;
}

struct SHTab {
  float c1[LMAXX+1][LMAXX+1];
  float c2[LMAXX+1][LMAXX+1];
  float qmm[LMAXX+1];
  float qnx[LMAXX+1];
};

constexpr SHTab makeTab(){
  SHTab t{};
  for(int m=0;m<=LMAXX;++m){
    double q = ((m&1)?-1.0:1.0)*dfactd(2*m-1);
    t.qmm[m]=(float)(q*CPf(m,m));
    t.qnx[m]=(m<LMAXX)?(float)((2.0*m+1.0)*q*CPf(m,m+1)):0.0f;
    for(int l=m+2;l<=LMAXX;++l){
      t.c1[m][l]=(float)((2.0*l-1.0)/(double)(l-m)*CPf(m,l)/CPf(m,l-1));
      t.c2[m][l]=(float)((double)(l+m-1)/(double)(l-m)*CPf(m,l)/CPf(m,l-2));
    }
  }
  return t;
}
constexpr SHTab SHT = makeTab();

// block offsets for even l: l=0,2,4,6,8 -> 0,1,6,15,28 ; idx(l,m)=offL(l)+l+m
constexpr int offL(int l){ return l==0?0 : (l==2?1 : (l==4?6 : (l==6?15 : 28))); }

template<int N, typename F>
__device__ __forceinline__ void cunroll(F&& f){
  if constexpr (N > 0){
    cunroll<N-1>(f);
    f(std::integral_constant<int, N-1>{});
  }
}

// ---------------- main kernel ----------------
// Grid = 2 * ntiles blocks: tile = bx>>1, half = bx&1. Each block: 64 voxels
// x 32 vectors (8/wave). Partials -> ws[bx*2880 .. +2880). Body identical to
// r7/r8 (proven <=170 VGPR, no spill); (256,3): 3 blocks/CU resident
// (LDS 48KB*3=144<=160), 3 waves/SIMD.
__global__ __launch_bounds__(256, 3)
void fodf_main(const float* __restrict__ image,
               const float* __restrict__ affine,
               const float* __restrict__ psf,
               const float* __restrict__ Mp,
               float* __restrict__ ws,
               int Nvox)
{
  __shared__ float red[WAVES_PB][VOXPB][CDIM+3];   // pad 45->48 floats

  const int tid  = threadIdx.x;
  const int lane = tid & 63;
  const int wvi  = __builtin_amdgcn_readfirstlane(tid >> 6); // wave id 0..3
  const int bx   = blockIdx.x;
  const int tileIdx = bx >> 1;
  const int half    = bx & 1;
  const int voxBase = tileIdx * VOXPB;
  const int vox  = voxBase + lane;
  const bool valid = vox < Nvox;

  // ---- per-voxel loads (one lane = one voxel) ----
  float img[CDIM];
  if (valid){
    const float* ip = image + (long long)vox * CDIM;
    #pragma unroll
    for(int c=0;c<CDIM;++c) img[c] = ip[c];
  } else {
    #pragma unroll
    for(int c=0;c<CDIM;++c) img[c] = 0.0f;
  }

  float a[9];
  if (valid){
    const float* ap = affine + (long long)vox * 9;
    #pragma unroll
    for(int i=0;i<9;++i) a[i] = ap[i];
  } else {
    #pragma unroll
    for(int i=0;i<9;++i) a[i] = (i%4==0) ? 1.0f : 0.0f;   // identity
  }

  // ---- 3x3 inverse via adjugate ----
  const float det = a[0]*(a[4]*a[8]-a[5]*a[7])
                  - a[1]*(a[3]*a[8]-a[5]*a[6])
                  + a[2]*(a[3]*a[7]-a[4]*a[6]);
  const float rdet = 1.0f/det;
  const float i00 =  (a[4]*a[8]-a[5]*a[7])*rdet;
  const float i01 = -(a[1]*a[8]-a[2]*a[7])*rdet;
  const float i02 =  (a[1]*a[5]-a[2]*a[4])*rdet;
  const float i10 = -(a[3]*a[8]-a[5]*a[6])*rdet;
  const float i11 =  (a[0]*a[8]-a[2]*a[6])*rdet;
  const float i12 = -(a[0]*a[5]-a[2]*a[3])*rdet;
  const float i20 =  (a[3]*a[7]-a[4]*a[6])*rdet;
  const float i21 = -(a[0]*a[7]-a[1]*a[6])*rdet;
  const float i22 =  (a[0]*a[4]-a[1]*a[3])*rdet;

  float acc[CDIM];
  #pragma unroll
  for(int c=0;c<CDIM;++c) acc[c]=0.0f;

  // ---- this block-half's vectors: 8 per wave (v wave-uniform -> s_loads) ----
  const int vbase = half*(VDIM/NSPLIT) + wvi * VPT;
  #pragma unroll 4
  for(int k=0;k<VPT;++k){
    const int v = vbase + k;
    const float sxv = psf[3*v+0];
    const float syv = psf[3*v+1];
    const float szv = psf[3*v+2];

    // vi_hat = A^{-1} @ psf[v]
    const float hx = fmaf(i00,sxv, fmaf(i01,syv, i02*szv));
    const float hy = fmaf(i10,sxv, fmaf(i11,syv, i12*szv));
    const float hz = fmaf(i20,sxv, fmaf(i21,syv, i22*szv));

    const float r2  = fmaf(hx,hx, fmaf(hy,hy, hz*hz));
    const float rin = rsqrtf(r2 + 1e-12f);        // hw rsqrt: fine vs 1.6e-2 tol
    // xyz -> yzx permute, then normalize
    const float px = hy*rin;
    const float py = hz*rin;
    const float pz = hx*rin;

    const float modv = r2 * rin * det;            // sqrt(r2)*det == r2*rsqrt(r2)*det

    // w[v] = dot(M_p[v,:], img) — M_p row is wave-uniform (SGPR broadcast)
    const float* Mrow = Mp + v*CDIM;
    float w0=0.f,w1=0.f,w2=0.f,w3=0.f;
    #pragma unroll
    for(int c=0;c<44;c+=4){
      w0 = fmaf(Mrow[c+0], img[c+0], w0);
      w1 = fmaf(Mrow[c+1], img[c+1], w1);
      w2 = fmaf(Mrow[c+2], img[c+2], w2);
      w3 = fmaf(Mrow[c+3], img[c+3], w3);
    }
    w0 = fmaf(Mrow[44], img[44], w0);
    const float wval = (w0+w1)+(w2+w3);
    const float wmod = modv * wval;

    // A/B Chebyshev recurrence, seeded with wmod (linear -> fa/fb muls free)
    float Aa[LMAXX+1], Bb[LMAXX+1];
    Aa[0]=wmod; Bb[0]=0.0f;
    cunroll<LMAXX>([&](auto Mc){
      constexpr int M = decltype(Mc)::value + 1;
      Aa[M] = fmaf(px, Aa[M-1], -(py*Bb[M-1]));
      Bb[M] = fmaf(px, Bb[M-1],  (py*Aa[M-1]));
    });

    // per |m|: CP-rescaled Q recurrence + fused accumulate
    cunroll<LMAXX+1>([&](auto AMc){
      constexpr int AM = decltype(AMc)::value;
      const float fa = Aa[AM];
      const float fb = Bb[AM];
      float qp2 = SHT.qmm[AM];
      float qp1 = SHT.qnx[AM]*pz;

      if constexpr ((AM&1)==0){
        if constexpr (AM==0){
          acc[0] = fmaf(qp2, fa, acc[0]);
        } else {
          acc[offL(AM)+2*AM] = fmaf(qp2, fa, acc[offL(AM)+2*AM]);
          acc[offL(AM)+0   ] = fmaf(qp2, fb, acc[offL(AM)+0   ]);
        }
      }
      if constexpr (AM<LMAXX && (((AM+1)&1)==0)){
        constexpr int L = AM+1;
        acc[offL(L)+L+AM] = fmaf(qp1, fa, acc[offL(L)+L+AM]);
        acc[offL(L)+L-AM] = fmaf(qp1, fb, acc[offL(L)+L-AM]);
      }

      constexpr int CNT = (LMAXX-AM-1) > 0 ? (LMAXX-AM-1) : 0;
      cunroll<CNT>([&](auto Lc){
        constexpr int L = AM + 2 + decltype(Lc)::value;
        constexpr float C1 = SHT.c1[AM][L];
        constexpr float C2 = SHT.c2[AM][L];
        const float q = fmaf(C1*pz, qp1, -(C2*qp2));
        qp2 = qp1; qp1 = q;
        if constexpr ((L&1)==0){
          if constexpr (AM==0){
            acc[offL(L)+L] = fmaf(q, fa, acc[offL(L)+L]);
          } else {
            acc[offL(L)+L+AM] = fmaf(q, fa, acc[offL(L)+L+AM]);
            acc[offL(L)+L-AM] = fmaf(q, fb, acc[offL(L)+L-AM]);
          }
        }
      });
    });
  }

  // ---- cross-wave reduction over this block's 4 vector-splits ----
  #pragma unroll
  for(int c=0;c<CDIM;++c) red[wvi][lane][c] = acc[c];
  __syncthreads();

  // ---- partial store (coalesced, unguarded: invalid lanes contributed 0) ----
  float* wp = ws + (size_t)bx * TILEF;
  for(int i = tid; i < TILEF; i += 256){
    const int vx = i / CDIM;
    const int c  = i - vx*CDIM;
    wp[i] = red[0][vx][c] + red[1][vx][c] + red[2][vx][c] + red[3][vx][c];
  }
}

// ---------------- combine kernel: out = wsA + wsB (float4) ----------------
__global__ __launch_bounds__(256)
void fodf_combine(const float* __restrict__ ws,
                  float* __restrict__ out,
                  int total)                       // total = Nvox*CDIM
{
  const int n4 = total >> 2;
  const int i4 = blockIdx.x * 256 + threadIdx.x;
  const float4* ws4 = (const float4*)ws;
  float4* out4 = (float4*)out;
  constexpr int T4 = TILEF / 4;                    // 720
  if (i4 < n4){
    const int t = i4 / T4;
    const int j = i4 - t * T4;
    const float4 a = ws4[(size_t)(2*t  )*T4 + j];
    const float4 b = ws4[(size_t)(2*t+1)*T4 + j];
    out4[i4] = make_float4(a.x+b.x, a.y+b.y, a.z+b.z, a.w+b.w);
  }
  // scalar tail (total % 4), handled by one thread
  if (i4 == 0){
    for (int r = n4*4; r < total; ++r){
      const int t = r / TILEF;
      const int j = r - t*TILEF;
      out[r] = ws[(size_t)(2*t)*TILEF + j] + ws[(size_t)(2*t+1)*TILEF + j];
    }
  }
}

// ---------------- launch ----------------
extern "C" void kernel_launch(void* const* d_in, const int* in_sizes, int n_in,
                              void* d_out, int out_size, void* d_ws, size_t ws_size,
                              hipStream_t stream)
{
  const float* image  = (const float*)d_in[0];
  const float* affine = (const float*)d_in[1];
  const float* psf    = (const float*)d_in[2];
  const float* Mp     = (const float*)d_in[3];
  float* out = (float*)d_out;
  float* ws  = (float*)d_ws;      // 1024 * 2880 floats = 11.8 MB << ws_size

  const int Nvox   = in_sizes[0] / CDIM;
  const int ntiles = (Nvox + VOXPB - 1) / VOXPB;
  const int total  = Nvox * CDIM;
  const int n4     = total >> 2;

  hipLaunchKernelGGL(fodf_main, dim3(ntiles * NSPLIT), dim3(256), 0, stream,
                     image, affine, psf, Mp, ws, Nvox);
  hipLaunchKernelGGL(fodf_combine, dim3((n4 + 255)/256), dim3(256), 0, stream,
                     ws, out, total);
}

// Round 12
// 82.713 us; speedup vs baseline: 1.0729x; 1.0729x over previous
//
#include <hip/hip_runtime.h>
#include <type_traits>
#include <utility>

#define CDIM   45
#define LMAXX  8
#define WAVES_PB 4
#define VOXPB  64
#define VDIM   64
#define VPT    (VDIM / WAVES_PB)
#define IMGP   48                      // padded LDS row (16B-aligned per lane)
#define AFFP   12                      // padded affine row

// ---------------- compile-time SH constant tables ----------------
// Normalization CP[m][l] folded INTO the Q-recurrence (p_l = Q_l * CP[m][l]);
// wmod folded into the A/B recurrence seed.
constexpr double PI_D = 3.14159265358979323846;

constexpr double dfactd(int n){ double o=1.0; for(int k=n;k>1;k-=2) o*=k; return o; }
constexpr double factd (int n){ double o=1.0; for(int k=2;k<=n;++k) o*=k; return o; }
constexpr double csqrtd(double x){
  if(x<=0.0) return 0.0;
  double g = x>1.0 ? x : 1.0;
  for(int i=0;i<200;++i) g = 0.5*(g + x/g);
  return g;
}

constexpr double CPf(int m, int l){
  double K = csqrtd((2.0*l+1.0)/(4.0*PI_D)*factd(l-m)/factd(l+m));
  if (m==0) return K;
  return ((m&1)?-1.0:1.0)*csqrtd(2.0)*K;
}

struct SHTab {
  float c1[LMAXX+1][LMAXX+1];
  float c2[LMAXX+1][LMAXX+1];
  float qmm[LMAXX+1];
  float qnx[LMAXX+1];
};

constexpr SHTab makeTab(){
  SHTab t{};
  for(int m=0;m<=LMAXX;++m){
    double q = ((m&1)?-1.0:1.0)*dfactd(2*m-1);
    t.qmm[m]=(float)(q*CPf(m,m));
    t.qnx[m]=(m<LMAXX)?(float)((2.0*m+1.0)*q*CPf(m,m+1)):0.0f;
    for(int l=m+2;l<=LMAXX;++l){
      t.c1[m][l]=(float)((2.0*l-1.0)/(double)(l-m)*CPf(m,l)/CPf(m,l-1));
      t.c2[m][l]=(float)((double)(l+m-1)/(double)(l-m)*CPf(m,l)/CPf(m,l-2));
    }
  }
  return t;
}
constexpr SHTab SHT = makeTab();

// block offsets for even l: l=0,2,4,6,8 -> 0,1,6,15,28 ; idx(l,m)=offL(l)+l+m
constexpr int offL(int l){ return l==0?0 : (l==2?1 : (l==4?6 : (l==6?15 : 28))); }

template<int N, typename F>
__device__ __forceinline__ void cunroll(F&& f){
  if constexpr (N > 0){
    cunroll<N-1>(f);
    f(std::integral_constant<int, N-1>{});
  }
}

// ---------------- kernel ----------------
// r8 body; ONLY the input path changed: img/affine staged coalesced into LDS
// (kills the 64-line-per-instr TCP gather + 4x cross-wave redundancy).
__global__ __launch_bounds__(256, 2)
void fodf_reorient_kernel(const float* __restrict__ image,
                          const float* __restrict__ affine,
                          const float* __restrict__ psf,
                          const float* __restrict__ Mp,
                          float* __restrict__ out,
                          int Nvox)
{
  __shared__ float simg[VOXPB*IMGP];               // 12.3 KiB (rows padded to 48)
  __shared__ float saff[VOXPB*AFFP];               //  3.0 KiB (rows padded to 12)
  __shared__ float red[WAVES_PB][VOXPB][CDIM+3];   // 48 KiB (pad 45->48)

  const int tid  = threadIdx.x;
  const int lane = tid & 63;
  const int wvi  = __builtin_amdgcn_readfirstlane(tid >> 6); // wave id 0..3
  const int voxBase = blockIdx.x * VOXPB;

  // ---- cooperative COALESCED staging (global reads linear in f) ----
  {
    const int nv   = min(VOXPB, Nvox - voxBase);
    const float* gi = image + (size_t)voxBase * CDIM;
    const int limi = nv * CDIM;
    #pragma unroll 1
    for (int f = tid; f < limi; f += 256){
      const int vx = f / CDIM;                     // magic-mul
      simg[vx*IMGP + (f - vx*CDIM)] = gi[f];
    }
    const float* ga = affine + (size_t)voxBase * 9;
    const int lima = nv * 9;
    #pragma unroll 1
    for (int f = tid; f < lima; f += 256){
      const int vx = f / 9;
      saff[vx*AFFP + (f - vx*9)] = ga[f];
    }
  }
  __syncthreads();

  // ---- per-lane regs from LDS (rows 16B-aligned -> ds_read_b128) ----
  float img[CDIM];
  #pragma unroll
  for(int c=0;c<CDIM;++c) img[c] = simg[lane*IMGP + c];
  float a[9];
  #pragma unroll
  for(int i=0;i<9;++i) a[i] = saff[lane*AFFP + i];

  // ---- 3x3 inverse via adjugate ----
  const float det = a[0]*(a[4]*a[8]-a[5]*a[7])
                  - a[1]*(a[3]*a[8]-a[5]*a[6])
                  + a[2]*(a[3]*a[7]-a[4]*a[6]);
  const float rdet = 1.0f/det;
  const float i00 =  (a[4]*a[8]-a[5]*a[7])*rdet;
  const float i01 = -(a[1]*a[8]-a[2]*a[7])*rdet;
  const float i02 =  (a[1]*a[5]-a[2]*a[4])*rdet;
  const float i10 = -(a[3]*a[8]-a[5]*a[6])*rdet;
  const float i11 =  (a[0]*a[8]-a[2]*a[6])*rdet;
  const float i12 = -(a[0]*a[5]-a[2]*a[3])*rdet;
  const float i20 =  (a[3]*a[7]-a[4]*a[6])*rdet;
  const float i21 = -(a[0]*a[7]-a[1]*a[6])*rdet;
  const float i22 =  (a[0]*a[4]-a[1]*a[3])*rdet;

  float acc[CDIM];
  #pragma unroll
  for(int c=0;c<CDIM;++c) acc[c]=0.0f;

  // ---- loop over this wave's 16 PSF vectors (v wave-uniform -> s_loads) ----
  const int vbase = wvi * VPT;
  #pragma unroll 4
  for(int k=0;k<VPT;++k){
    const int v = vbase + k;
    const float sxv = psf[3*v+0];
    const float syv = psf[3*v+1];
    const float szv = psf[3*v+2];

    // vi_hat = A^{-1} @ psf[v]
    const float hx = fmaf(i00,sxv, fmaf(i01,syv, i02*szv));
    const float hy = fmaf(i10,sxv, fmaf(i11,syv, i12*szv));
    const float hz = fmaf(i20,sxv, fmaf(i21,syv, i22*szv));

    const float r2  = fmaf(hx,hx, fmaf(hy,hy, hz*hz));
    const float rin = rsqrtf(r2 + 1e-12f);        // hw rsqrt: fine vs 1.6e-2 tol
    // xyz -> yzx permute, then normalize
    const float px = hy*rin;
    const float py = hz*rin;
    const float pz = hx*rin;

    const float modv = r2 * rin * det;            // sqrt(r2)*det == r2*rsqrt(r2)*det

    // w[v] = dot(M_p[v,:], img) — M_p row is wave-uniform (SGPR broadcast)
    const float* Mrow = Mp + v*CDIM;
    float w0=0.f,w1=0.f,w2=0.f,w3=0.f;
    #pragma unroll
    for(int c=0;c<44;c+=4){
      w0 = fmaf(Mrow[c+0], img[c+0], w0);
      w1 = fmaf(Mrow[c+1], img[c+1], w1);
      w2 = fmaf(Mrow[c+2], img[c+2], w2);
      w3 = fmaf(Mrow[c+3], img[c+3], w3);
    }
    w0 = fmaf(Mrow[44], img[44], w0);
    const float wval = (w0+w1)+(w2+w3);
    const float wmod = modv * wval;

    // A/B Chebyshev recurrence, seeded with wmod (linear -> fa/fb muls free)
    float Aa[LMAXX+1], Bb[LMAXX+1];
    Aa[0]=wmod; Bb[0]=0.0f;
    cunroll<LMAXX>([&](auto Mc){
      constexpr int M = decltype(Mc)::value + 1;
      Aa[M] = fmaf(px, Aa[M-1], -(py*Bb[M-1]));
      Bb[M] = fmaf(px, Bb[M-1],  (py*Aa[M-1]));
    });

    // per |m|: CP-rescaled Q recurrence + fused accumulate
    cunroll<LMAXX+1>([&](auto AMc){
      constexpr int AM = decltype(AMc)::value;
      const float fa = Aa[AM];
      const float fb = Bb[AM];
      float qp2 = SHT.qmm[AM];
      float qp1 = SHT.qnx[AM]*pz;

      if constexpr ((AM&1)==0){
        if constexpr (AM==0){
          acc[0] = fmaf(qp2, fa, acc[0]);
        } else {
          acc[offL(AM)+2*AM] = fmaf(qp2, fa, acc[offL(AM)+2*AM]);
          acc[offL(AM)+0   ] = fmaf(qp2, fb, acc[offL(AM)+0   ]);
        }
      }
      if constexpr (AM<LMAXX && (((AM+1)&1)==0)){
        constexpr int L = AM+1;
        acc[offL(L)+L+AM] = fmaf(qp1, fa, acc[offL(L)+L+AM]);
        acc[offL(L)+L-AM] = fmaf(qp1, fb, acc[offL(L)+L-AM]);
      }

      constexpr int CNT = (LMAXX-AM-1) > 0 ? (LMAXX-AM-1) : 0;
      cunroll<CNT>([&](auto Lc){
        constexpr int L = AM + 2 + decltype(Lc)::value;
        constexpr float C1 = SHT.c1[AM][L];
        constexpr float C2 = SHT.c2[AM][L];
        const float q = fmaf(C1*pz, qp1, -(C2*qp2));
        qp2 = qp1; qp1 = q;
        if constexpr ((L&1)==0){
          if constexpr (AM==0){
            acc[offL(L)+L] = fmaf(q, fa, acc[offL(L)+L]);
          } else {
            acc[offL(L)+L+AM] = fmaf(q, fa, acc[offL(L)+L+AM]);
            acc[offL(L)+L-AM] = fmaf(q, fb, acc[offL(L)+L-AM]);
          }
        }
      });
    });
  }

  // ---- cross-wave reduction over the 4 vector-splits ----
  #pragma unroll
  for(int c=0;c<CDIM;++c) red[wvi][lane][c] = acc[c];
  __syncthreads();

  const int total = VOXPB * CDIM;
  for(int i = tid; i < total; i += 256){
    const int vx = i / CDIM;
    if (voxBase + vx < Nvox){
      const int c = i - vx*CDIM;
      const float s = red[0][vx][c] + red[1][vx][c]
                    + red[2][vx][c] + red[3][vx][c];
      out[(long long)voxBase*CDIM + i] = s;
    }
  }
}

// ---------------- launch ----------------
extern "C" void kernel_launch(void* const* d_in, const int* in_sizes, int n_in,
                              void* d_out, int out_size, void* d_ws, size_t ws_size,
                              hipStream_t stream)
{
  const float* image  = (const float*)d_in[0];
  const float* affine = (const float*)d_in[1];
  const float* psf    = (const float*)d_in[2];
  const float* Mp     = (const float*)d_in[3];
  float* out = (float*)d_out;

  const int Nvox = in_sizes[0] / CDIM;
  const int blocks = (Nvox + VOXPB - 1) / VOXPB;

  hipLaunchKernelGGL(fodf_reorient_kernel, dim3(blocks), dim3(256), 0, stream,
                     image, affine, psf, Mp, out, Nvox);
}

// Round 13
// 81.909 us; speedup vs baseline: 1.0834x; 1.0098x over previous
//
#include <hip/hip_runtime.h>
#include <type_traits>
#include <utility>

#define CDIM   45
#define LMAXX  8
#define WAVES_PB 4
#define VOXPB  64
#define VDIM   64
#define VPT    (VDIM / WAVES_PB)

// ---------------- compile-time SH constant tables ----------------
// Normalization CP[m][l] folded INTO the Q-recurrence (p_l = Q_l * CP[m][l]);
// wmod folded into the A/B recurrence seed.
constexpr double PI_D = 3.14159265358979323846;

constexpr double dfactd(int n){ double o=1.0; for(int k=n;k>1;k-=2) o*=k; return o; }
constexpr double factd (int n){ double o=1.0; for(int k=2;k<=n;++k) o*=k; return o; }
constexpr double csqrtd(double x){
  if(x<=0.0) return 0.0;
  double g = x>1.0 ? x : 1.0;
  for(int i=0;i<200;++i) g = 0.5*(g + x/g);
  return g;
}

constexpr double CPf(int m, int l){
  double K = csqrtd((2.0*l+1.0)/(4.0*PI_D)*factd(l-m)/factd(l+m));
  if (m==0) return K;
  return ((m&1)?-1.0:1.0)*csqrtd(2.0)*K;
}

struct SHTab {
  float c1[LMAXX+1][LMAXX+1];
  float c2[LMAXX+1][LMAXX+1];
  float qmm[LMAXX+1];
  float qnx[LMAXX+1];
};

constexpr SHTab makeTab(){
  SHTab t{};
  for(int m=0;m<=LMAXX;++m){
    double q = ((m&1)?-1.0:1.0)*dfactd(2*m-1);
    t.qmm[m]=(float)(q*CPf(m,m));
    t.qnx[m]=(m<LMAXX)?(float)((2.0*m+1.0)*q*CPf(m,m+1)):0.0f;
    for(int l=m+2;l<=LMAXX;++l){
      t.c1[m][l]=(float)((2.0*l-1.0)/(double)(l-m)*CPf(m,l)/CPf(m,l-1));
      t.c2[m][l]=(float)((double)(l+m-1)/(double)(l-m)*CPf(m,l)/CPf(m,l-2));
    }
  }
  return t;
}
constexpr SHTab SHT = makeTab();

// block offsets for even l: l=0,2,4,6,8 -> 0,1,6,15,28 ; idx(l,m)=offL(l)+l+m
constexpr int offL(int l){ return l==0?0 : (l==2?1 : (l==4?6 : (l==6?15 : 28))); }

template<int N, typename F>
__device__ __forceinline__ void cunroll(F&& f){
  if constexpr (N > 0){
    cunroll<N-1>(f);
    f(std::integral_constant<int, N-1>{});
  }
}

// ---------------- kernel ----------------
// r8 body; ONE change: Mp staged to LDS once per block (fully-unrolled
// coalesced loads, all in flight), inner loop reads rows via wave-uniform
// ds_read broadcast -> kills per-iteration s_load serialization (SGPR-bound,
// which is why r7's unroll-4 and VALU trim nulled).
__global__ __launch_bounds__(256, 3)
void fodf_reorient_kernel(const float* __restrict__ image,
                          const float* __restrict__ affine,
                          const float* __restrict__ psf,
                          const float* __restrict__ Mp,
                          float* __restrict__ out,
                          int Nvox)
{
  __shared__ float sMp[VDIM*CDIM];                 // 11.25 KiB, [v][45] linear
  __shared__ float red[WAVES_PB][VOXPB][CDIM+3];   // 48 KiB (pad 45->48)

  const int tid  = threadIdx.x;
  const int lane = tid & 63;
  const int wvi  = __builtin_amdgcn_readfirstlane(tid >> 6); // wave id 0..3
  const int voxBase = blockIdx.x * VOXPB;
  const int vox  = voxBase + lane;
  const bool valid = vox < Nvox;

  // ---- stage Mp coalesced; FULL unroll -> all loads in flight (no serial
  //      latency exposure, cf. r12's unroll-1 mistake) ----
  #pragma unroll
  for (int f = tid; f < VDIM*CDIM; f += 256) sMp[f] = Mp[f];

  // ---- per-voxel loads (one lane = one voxel) ----
  float img[CDIM];
  if (valid){
    const float* ip = image + (long long)vox * CDIM;
    #pragma unroll
    for(int c=0;c<CDIM;++c) img[c] = ip[c];
  } else {
    #pragma unroll
    for(int c=0;c<CDIM;++c) img[c] = 0.0f;
  }

  float a[9];
  if (valid){
    const float* ap = affine + (long long)vox * 9;
    #pragma unroll
    for(int i=0;i<9;++i) a[i] = ap[i];
  } else {
    #pragma unroll
    for(int i=0;i<9;++i) a[i] = (i%4==0) ? 1.0f : 0.0f;   // identity
  }

  // ---- 3x3 inverse via adjugate ----
  const float det = a[0]*(a[4]*a[8]-a[5]*a[7])
                  - a[1]*(a[3]*a[8]-a[5]*a[6])
                  + a[2]*(a[3]*a[7]-a[4]*a[6]);
  const float rdet = 1.0f/det;
  const float i00 =  (a[4]*a[8]-a[5]*a[7])*rdet;
  const float i01 = -(a[1]*a[8]-a[2]*a[7])*rdet;
  const float i02 =  (a[1]*a[5]-a[2]*a[4])*rdet;
  const float i10 = -(a[3]*a[8]-a[5]*a[6])*rdet;
  const float i11 =  (a[0]*a[8]-a[2]*a[6])*rdet;
  const float i12 = -(a[0]*a[5]-a[2]*a[3])*rdet;
  const float i20 =  (a[3]*a[7]-a[4]*a[6])*rdet;
  const float i21 = -(a[0]*a[7]-a[1]*a[6])*rdet;
  const float i22 =  (a[0]*a[4]-a[1]*a[3])*rdet;

  float acc[CDIM];
  #pragma unroll
  for(int c=0;c<CDIM;++c) acc[c]=0.0f;

  __syncthreads();   // sMp ready

  // ---- loop over this wave's 16 PSF vectors ----
  const int vbase = wvi * VPT;
  #pragma unroll 2
  for(int k=0;k<VPT;++k){
    const int v = vbase + k;
    const float sxv = psf[3*v+0];
    const float syv = psf[3*v+1];
    const float szv = psf[3*v+2];

    // vi_hat = A^{-1} @ psf[v]
    const float hx = fmaf(i00,sxv, fmaf(i01,syv, i02*szv));
    const float hy = fmaf(i10,sxv, fmaf(i11,syv, i12*szv));
    const float hz = fmaf(i20,sxv, fmaf(i21,syv, i22*szv));

    const float r2  = fmaf(hx,hx, fmaf(hy,hy, hz*hz));
    const float rin = rsqrtf(r2 + 1e-12f);        // hw rsqrt: fine vs 1.6e-2 tol
    // xyz -> yzx permute, then normalize
    const float px = hy*rin;
    const float py = hz*rin;
    const float pz = hx*rin;

    const float modv = r2 * rin * det;            // sqrt(r2)*det == r2*rsqrt(r2)*det

    // w[v] = dot(M_p[v,:], img) — Mp row from LDS, wave-uniform broadcast
    const float* Mrow = &sMp[v*CDIM];
    float w0=0.f,w1=0.f,w2=0.f,w3=0.f;
    #pragma unroll
    for(int c=0;c<44;c+=4){
      w0 = fmaf(Mrow[c+0], img[c+0], w0);
      w1 = fmaf(Mrow[c+1], img[c+1], w1);
      w2 = fmaf(Mrow[c+2], img[c+2], w2);
      w3 = fmaf(Mrow[c+3], img[c+3], w3);
    }
    w0 = fmaf(Mrow[44], img[44], w0);
    const float wval = (w0+w1)+(w2+w3);
    const float wmod = modv * wval;

    // A/B Chebyshev recurrence, seeded with wmod (linear -> fa/fb muls free)
    float Aa[LMAXX+1], Bb[LMAXX+1];
    Aa[0]=wmod; Bb[0]=0.0f;
    cunroll<LMAXX>([&](auto Mc){
      constexpr int M = decltype(Mc)::value + 1;
      Aa[M] = fmaf(px, Aa[M-1], -(py*Bb[M-1]));
      Bb[M] = fmaf(px, Bb[M-1],  (py*Aa[M-1]));
    });

    // per |m|: CP-rescaled Q recurrence + fused accumulate
    cunroll<LMAXX+1>([&](auto AMc){
      constexpr int AM = decltype(AMc)::value;
      const float fa = Aa[AM];
      const float fb = Bb[AM];
      float qp2 = SHT.qmm[AM];
      float qp1 = SHT.qnx[AM]*pz;

      if constexpr ((AM&1)==0){
        if constexpr (AM==0){
          acc[0] = fmaf(qp2, fa, acc[0]);
        } else {
          acc[offL(AM)+2*AM] = fmaf(qp2, fa, acc[offL(AM)+2*AM]);
          acc[offL(AM)+0   ] = fmaf(qp2, fb, acc[offL(AM)+0   ]);
        }
      }
      if constexpr (AM<LMAXX && (((AM+1)&1)==0)){
        constexpr int L = AM+1;
        acc[offL(L)+L+AM] = fmaf(qp1, fa, acc[offL(L)+L+AM]);
        acc[offL(L)+L-AM] = fmaf(qp1, fb, acc[offL(L)+L-AM]);
      }

      constexpr int CNT = (LMAXX-AM-1) > 0 ? (LMAXX-AM-1) : 0;
      cunroll<CNT>([&](auto Lc){
        constexpr int L = AM + 2 + decltype(Lc)::value;
        constexpr float C1 = SHT.c1[AM][L];
        constexpr float C2 = SHT.c2[AM][L];
        const float q = fmaf(C1*pz, qp1, -(C2*qp2));
        qp2 = qp1; qp1 = q;
        if constexpr ((L&1)==0){
          if constexpr (AM==0){
            acc[offL(L)+L] = fmaf(q, fa, acc[offL(L)+L]);
          } else {
            acc[offL(L)+L+AM] = fmaf(q, fa, acc[offL(L)+L+AM]);
            acc[offL(L)+L-AM] = fmaf(q, fb, acc[offL(L)+L-AM]);
          }
        }
      });
    });
  }

  // ---- cross-wave reduction over the 4 vector-splits ----
  #pragma unroll
  for(int c=0;c<CDIM;++c) red[wvi][lane][c] = acc[c];
  __syncthreads();

  const int total = VOXPB * CDIM;
  for(int i = tid; i < total; i += 256){
    const int vx = i / CDIM;
    if (voxBase + vx < Nvox){
      const int c = i - vx*CDIM;
      const float s = red[0][vx][c] + red[1][vx][c]
                    + red[2][vx][c] + red[3][vx][c];
      out[(long long)voxBase*CDIM + i] = s;
    }
  }
}

// ---------------- launch ----------------
extern "C" void kernel_launch(void* const* d_in, const int* in_sizes, int n_in,
                              void* d_out, int out_size, void* d_ws, size_t ws_size,
                              hipStream_t stream)
{
  const float* image  = (const float*)d_in[0];
  const float* affine = (const float*)d_in[1];
  const float* psf    = (const float*)d_in[2];
  const float* Mp     = (const float*)d_in[3];
  float* out = (float*)d_out;

  const int Nvox = in_sizes[0] / CDIM;
  const int blocks = (Nvox + VOXPB - 1) / VOXPB;

  hipLaunchKernelGGL(fodf_reorient_kernel, dim3(blocks), dim3(256), 0, stream,
                     image, affine, psf, Mp, out, Nvox);
}

// Round 14
// 79.463 us; speedup vs baseline: 1.1168x; 1.0308x over previous
//
#include <hip/hip_runtime.h>
#include <type_traits>
#include <utility>

#define CDIM   45
#define LMAXX  8
#define WAVES_PB 4
#define VOXPB  64
#define VDIM   64
#define VPT    (VDIM / WAVES_PB)

// ---------------- compile-time SH constant tables ----------------
// Normalization CP[m][l] folded INTO the Q-recurrence (p_l = Q_l * CP[m][l]);
// wmod folded into the A/B recurrence seed.
constexpr double PI_D = 3.14159265358979323846;

constexpr double dfactd(int n){ double o=1.0; for(int k=n;k>1;k-=2) o*=k; return o; }
constexpr double factd (int n){ double o=1.0; for(int k=2;k<=n;++k) o*=k; return o; }
constexpr double csqrtd(double x){
  if(x<=0.0) return 0.0;
  double g = x>1.0 ? x : 1.0;
  for(int i=0;i<200;++i) g = 0.5*(g + x/g);
  return g;
}

constexpr double CPf(int m, int l){
  double K = csqrtd((2.0*l+1.0)/(4.0*PI_D)*factd(l-m)/factd(l+m));
  if (m==0) return K;
  return ((m&1)?-1.0:1.0)*csqrtd(2.0)*K;
}

struct SHTab {
  float c1[LMAXX+1][LMAXX+1];
  float c2[LMAXX+1][LMAXX+1];
  float qmm[LMAXX+1];
  float qnx[LMAXX+1];
};

constexpr SHTab makeTab(){
  SHTab t{};
  for(int m=0;m<=LMAXX;++m){
    double q = ((m&1)?-1.0:1.0)*dfactd(2*m-1);
    t.qmm[m]=(float)(q*CPf(m,m));
    t.qnx[m]=(m<LMAXX)?(float)((2.0*m+1.0)*q*CPf(m,m+1)):0.0f;
    for(int l=m+2;l<=LMAXX;++l){
      t.c1[m][l]=(float)((2.0*l-1.0)/(double)(l-m)*CPf(m,l)/CPf(m,l-1));
      t.c2[m][l]=(float)((double)(l+m-1)/(double)(l-m)*CPf(m,l)/CPf(m,l-2));
    }
  }
  return t;
}
constexpr SHTab SHT = makeTab();

// block offsets for even l: l=0,2,4,6,8 -> 0,1,6,15,28 ; idx(l,m)=offL(l)+l+m
constexpr int offL(int l){ return l==0?0 : (l==2?1 : (l==4?6 : (l==6?15 : 28))); }

template<int N, typename F>
__device__ __forceinline__ void cunroll(F&& f){
  if constexpr (N > 0){
    cunroll<N-1>(f);
    f(std::integral_constant<int, N-1>{});
  }
}

// ---------------- kernel ----------------
// Final configuration (empirical best, r8 = 79.49us). Structure:
// 256 thr = 4 waves/block; lane = voxel, each wave 16 PSF vectors; store
// epilogue over padded LDS. Grid 512 blocks = 2/CU (grid-structural
// occupancy limit). All staging/split/occupancy variants measured slower.
__global__ __launch_bounds__(256, 3)
void fodf_reorient_kernel(const float* __restrict__ image,
                          const float* __restrict__ affine,
                          const float* __restrict__ psf,
                          const float* __restrict__ Mp,
                          float* __restrict__ out,
                          int Nvox)
{
  __shared__ float red[WAVES_PB][VOXPB][CDIM+3];   // pad 45->48 floats

  const int tid  = threadIdx.x;
  const int lane = tid & 63;
  const int wvi  = __builtin_amdgcn_readfirstlane(tid >> 6); // wave id 0..3
  const int voxBase = blockIdx.x * VOXPB;
  const int vox  = voxBase + lane;
  const bool valid = vox < Nvox;

  // ---- per-voxel loads (one lane = one voxel) ----
  float img[CDIM];
  if (valid){
    const float* ip = image + (long long)vox * CDIM;
    #pragma unroll
    for(int c=0;c<CDIM;++c) img[c] = ip[c];
  } else {
    #pragma unroll
    for(int c=0;c<CDIM;++c) img[c] = 0.0f;
  }

  float a[9];
  if (valid){
    const float* ap = affine + (long long)vox * 9;
    #pragma unroll
    for(int i=0;i<9;++i) a[i] = ap[i];
  } else {
    #pragma unroll
    for(int i=0;i<9;++i) a[i] = (i%4==0) ? 1.0f : 0.0f;   // identity
  }

  // ---- 3x3 inverse via adjugate ----
  const float det = a[0]*(a[4]*a[8]-a[5]*a[7])
                  - a[1]*(a[3]*a[8]-a[5]*a[6])
                  + a[2]*(a[3]*a[7]-a[4]*a[6]);
  const float rdet = 1.0f/det;
  const float i00 =  (a[4]*a[8]-a[5]*a[7])*rdet;
  const float i01 = -(a[1]*a[8]-a[2]*a[7])*rdet;
  const float i02 =  (a[1]*a[5]-a[2]*a[4])*rdet;
  const float i10 = -(a[3]*a[8]-a[5]*a[6])*rdet;
  const float i11 =  (a[0]*a[8]-a[2]*a[6])*rdet;
  const float i12 = -(a[0]*a[5]-a[2]*a[3])*rdet;
  const float i20 =  (a[3]*a[7]-a[4]*a[6])*rdet;
  const float i21 = -(a[0]*a[7]-a[1]*a[6])*rdet;
  const float i22 =  (a[0]*a[4]-a[1]*a[3])*rdet;

  float acc[CDIM];
  #pragma unroll
  for(int c=0;c<CDIM;++c) acc[c]=0.0f;

  // ---- loop over this wave's 16 PSF vectors (v is wave-uniform -> s_loads) ----
  const int vbase = wvi * VPT;
  #pragma unroll 4
  for(int k=0;k<VPT;++k){
    const int v = vbase + k;
    const float sxv = psf[3*v+0];
    const float syv = psf[3*v+1];
    const float szv = psf[3*v+2];

    // vi_hat = A^{-1} @ psf[v]
    const float hx = fmaf(i00,sxv, fmaf(i01,syv, i02*szv));
    const float hy = fmaf(i10,sxv, fmaf(i11,syv, i12*szv));
    const float hz = fmaf(i20,sxv, fmaf(i21,syv, i22*szv));

    const float r2  = fmaf(hx,hx, fmaf(hy,hy, hz*hz));
    const float rin = rsqrtf(r2 + 1e-12f);        // hw rsqrt: fine vs 1.6e-2 tol
    // xyz -> yzx permute, then normalize
    const float px = hy*rin;
    const float py = hz*rin;
    const float pz = hx*rin;

    const float modv = r2 * rin * det;            // sqrt(r2)*det == r2*rsqrt(r2)*det

    // w[v] = dot(M_p[v,:], img) — M_p row is wave-uniform (SGPR broadcast)
    const float* Mrow = Mp + v*CDIM;
    float w0=0.f,w1=0.f,w2=0.f,w3=0.f;
    #pragma unroll
    for(int c=0;c<44;c+=4){
      w0 = fmaf(Mrow[c+0], img[c+0], w0);
      w1 = fmaf(Mrow[c+1], img[c+1], w1);
      w2 = fmaf(Mrow[c+2], img[c+2], w2);
      w3 = fmaf(Mrow[c+3], img[c+3], w3);
    }
    w0 = fmaf(Mrow[44], img[44], w0);
    const float wval = (w0+w1)+(w2+w3);
    const float wmod = modv * wval;

    // A/B Chebyshev recurrence, seeded with wmod (linear -> fa/fb muls free)
    float Aa[LMAXX+1], Bb[LMAXX+1];
    Aa[0]=wmod; Bb[0]=0.0f;
    cunroll<LMAXX>([&](auto Mc){
      constexpr int M = decltype(Mc)::value + 1;
      Aa[M] = fmaf(px, Aa[M-1], -(py*Bb[M-1]));
      Bb[M] = fmaf(px, Bb[M-1],  (py*Aa[M-1]));
    });

    // per |m|: CP-rescaled Q recurrence + fused accumulate
    cunroll<LMAXX+1>([&](auto AMc){
      constexpr int AM = decltype(AMc)::value;
      const float fa = Aa[AM];
      const float fb = Bb[AM];
      float qp2 = SHT.qmm[AM];
      float qp1 = SHT.qnx[AM]*pz;

      if constexpr ((AM&1)==0){
        if constexpr (AM==0){
          acc[0] = fmaf(qp2, fa, acc[0]);
        } else {
          acc[offL(AM)+2*AM] = fmaf(qp2, fa, acc[offL(AM)+2*AM]);
          acc[offL(AM)+0   ] = fmaf(qp2, fb, acc[offL(AM)+0   ]);
        }
      }
      if constexpr (AM<LMAXX && (((AM+1)&1)==0)){
        constexpr int L = AM+1;
        acc[offL(L)+L+AM] = fmaf(qp1, fa, acc[offL(L)+L+AM]);
        acc[offL(L)+L-AM] = fmaf(qp1, fb, acc[offL(L)+L-AM]);
      }

      constexpr int CNT = (LMAXX-AM-1) > 0 ? (LMAXX-AM-1) : 0;
      cunroll<CNT>([&](auto Lc){
        constexpr int L = AM + 2 + decltype(Lc)::value;
        constexpr float C1 = SHT.c1[AM][L];
        constexpr float C2 = SHT.c2[AM][L];
        const float q = fmaf(C1*pz, qp1, -(C2*qp2));
        qp2 = qp1; qp1 = q;
        if constexpr ((L&1)==0){
          if constexpr (AM==0){
            acc[offL(L)+L] = fmaf(q, fa, acc[offL(L)+L]);
          } else {
            acc[offL(L)+L+AM] = fmaf(q, fa, acc[offL(L)+L+AM]);
            acc[offL(L)+L-AM] = fmaf(q, fb, acc[offL(L)+L-AM]);
          }
        }
      });
    });
  }

  // ---- cross-wave reduction over the 4 vector-splits ----
  #pragma unroll
  for(int c=0;c<CDIM;++c) red[wvi][lane][c] = acc[c];
  __syncthreads();

  const int total = VOXPB * CDIM;
  for(int i = tid; i < total; i += 256){
    const int vx = i / CDIM;
    if (voxBase + vx < Nvox){
      const int c = i - vx*CDIM;
      const float s = red[0][vx][c] + red[1][vx][c]
                    + red[2][vx][c] + red[3][vx][c];
      out[(long long)voxBase*CDIM + i] = s;
    }
  }
}

// ---------------- launch ----------------
extern "C" void kernel_launch(void* const* d_in, const int* in_sizes, int n_in,
                              void* d_out, int out_size, void* d_ws, size_t ws_size,
                              hipStream_t stream)
{
  const float* image  = (const float*)d_in[0];
  const float* affine = (const float*)d_in[1];
  const float* psf    = (const float*)d_in[2];
  const float* Mp     = (const float*)d_in[3];
  float* out = (float*)d_out;

  const int Nvox = in_sizes[0] / CDIM;
  const int blocks = (Nvox + VOXPB - 1) / VOXPB;

  hipLaunchKernelGGL(fodf_reorient_kernel, dim3(blocks), dim3(256), 0, stream,
                     image, affine, psf, Mp, out, Nvox);
}